// Round 5
// baseline (348.837 us; speedup 1.0000x reference)
//
#include <hip/hip_runtime.h>
#include <hip/hip_bf16.h>

#define Bb 4
#define Ss 2048
#define Dm 1024
#define Hh 16
#define DKk 64
#define DVv 64

using short8  = __attribute__((ext_vector_type(8))) short;
using short4v = __attribute__((ext_vector_type(4))) short;
using floatx4 = __attribute__((ext_vector_type(4))) float;

__device__ inline unsigned short f32_to_bf16(float f) {
    union { float f; unsigned int u; } x; x.f = f;
    unsigned int r = x.u + 0x7fffu + ((x.u >> 16) & 1u);
    return (unsigned short)(r >> 16);
}

// packed f32x2 -> bf16x2 (RNE), single instruction
__device__ inline unsigned int cvt_pk_bf16(float a, float b) {
    unsigned int r;
    asm("v_cvt_pk_bf16_f32 %0, %1, %2" : "=v"(r) : "v"(a), "v"(b));
    return r;
}

// async global->LDS DMA, 16B per lane (dest = wave-uniform base + lane*16)
__device__ inline void dma16(const unsigned short* g, unsigned short* l) {
    __builtin_amdgcn_global_load_lds(
        (const __attribute__((address_space(1))) void*)g,
        (__attribute__((address_space(3))) void*)l, 16, 0, 0);
}

// ---------------------------------------------------------------------------
// Weight transpose + cast (all 4 weights in one launch, z selects):
// W (K=1024, N=1024) fp32 -> Wt (N, K) bf16
// ---------------------------------------------------------------------------
__global__ __launch_bounds__(256) void transpose_w4(
        const float* __restrict__ W0, const float* __restrict__ W1,
        const float* __restrict__ W2, const float* __restrict__ W3,
        unsigned short* __restrict__ T0, unsigned short* __restrict__ T1,
        unsigned short* __restrict__ T2, unsigned short* __restrict__ T3) {
    const float* W; unsigned short* Wt;
    switch (blockIdx.z) {
        case 0: W = W0; Wt = T0; break;
        case 1: W = W1; Wt = T1; break;
        case 2: W = W2; Wt = T2; break;
        default: W = W3; Wt = T3; break;
    }
    __shared__ float tile[32][33];
    int n0 = blockIdx.x * 32, k0 = blockIdx.y * 32;
    int tx = threadIdx.x, ty = threadIdx.y;   // (32, 8)
    #pragma unroll
    for (int i = 0; i < 32; i += 8)
        tile[ty + i][tx] = W[(size_t)(k0 + ty + i) * Dm + n0 + tx];
    __syncthreads();
    #pragma unroll
    for (int i = 0; i < 32; i += 8)
        Wt[(size_t)(n0 + ty + i) * Dm + k0 + tx] = f32_to_bf16(tile[tx][ty + i]);
}

// ---------------------------------------------------------------------------
// Fused cast+projection GEMM, 2-phase pipelined (v2):
// C = cast_bf16(A fp32, 8192 x 1024) . Bt^T (+bias), z selects Q/K/V.
// Double-buffered LDS; staging for tile t+1 issued BEFORE compute of tile t;
// ONE barrier per K-step (its implicit vmcnt0/lgkm0 drains loads that had the
// whole MFMA phase to fly). A: global float4 -> regs (iter t-1) -> cvt+ds_write
// (iter t) -> read (iter t+1). B: global_load_lds into the nxt buffer.
// mode 0: out bf16 [((bb*H+h)*S + s)*64 + d]                  (Q, K layout)
// mode 1: out bf16 [(((bb*H+h)*32 + s/64)*64 + d)*64 + s%64]  (V tile-blocked)
// ---------------------------------------------------------------------------
__global__ __launch_bounds__(256) void gemm_proj_f32(
        const float* __restrict__ Aq, const float* __restrict__ Ak,
        const float* __restrict__ Av,
        const unsigned short* __restrict__ Btq, const unsigned short* __restrict__ Btk,
        const unsigned short* __restrict__ Btv,
        const float* __restrict__ bq, const float* __restrict__ bk,
        const float* __restrict__ bv,
        unsigned short* __restrict__ Oq, unsigned short* __restrict__ Ok,
        unsigned short* __restrict__ Ov) {
    const float* A; const unsigned short* Bt; const float* bias;
    unsigned short* Out; int mode;
    switch (blockIdx.z) {
        case 0:  A = Aq; Bt = Btq; bias = bq; Out = Oq; mode = 0; break;
        case 1:  A = Ak; Bt = Btk; bias = bk; Out = Ok; mode = 0; break;
        default: A = Av; Bt = Btv; bias = bv; Out = Ov; mode = 1; break;
    }
    const int wave = threadIdx.x >> 6;
    const int lane = threadIdx.x & 63;
    const int quad = lane >> 4;
    const int l16  = lane & 15;
    const int wr = wave & 1, wc = wave >> 1;
    const int m0 = blockIdx.x * 128;
    const int n0 = blockIdx.y * 128;

    __shared__ __align__(16) unsigned short Alds[2][4096];
    __shared__ __align__(16) unsigned short Blds[2][4096];

    // chunk mapping: 512 chunks of 16B (8 elems) per tile; 2 chunks/thread
    const float* Asrc[2];
    const unsigned short* Bsrc[2];
    int Adst[2], Bdst[2];
    #pragma unroll
    for (int i = 0; i < 2; i++) {
        int L = (wave * 2 + i) * 64 + lane;
        int row = L >> 2, cpr = L & 3;
        int csrc = cpr ^ ((row >> 1) & 3);
        Adst[i] = L * 8;                        // per-lane ds_write addr (ushorts)
        Bdst[i] = (wave * 2 + i) * 512;         // wave-uniform dma base
        Asrc[i] = A  + (size_t)(m0 + row) * Dm + csrc * 8;
        Bsrc[i] = Bt + (size_t)(n0 + row) * Dm + csrc * 8;
    }

    // fragment read offsets (swizzled)
    int aoff[4], boff[4];
    #pragma unroll
    for (int r = 0; r < 4; r++) {
        int row = wr * 64 + r * 16 + l16;
        aoff[r] = row * 32 + (quad ^ ((row >> 1) & 3)) * 8;
        row = wc * 64 + r * 16 + l16;
        boff[r] = row * 32 + (quad ^ ((row >> 1) & 3)) * 8;
    }

    // prologue: stage tile 0 (A regs -> cvt+write, B dma), prefetch A for tile 1
    float4 ar[2][2];
    #pragma unroll
    for (int i = 0; i < 2; i++) {
        ar[i][0] = *(const float4*)(Asrc[i]);
        ar[i][1] = *(const float4*)(Asrc[i] + 4);
    }
    #pragma unroll
    for (int i = 0; i < 2; i++) {
        dma16(Bsrc[i], &Blds[0][Bdst[i]]);
        union { short8 v; unsigned int u[4]; } w;
        w.u[0] = cvt_pk_bf16(ar[i][0].x, ar[i][0].y);
        w.u[1] = cvt_pk_bf16(ar[i][0].z, ar[i][0].w);
        w.u[2] = cvt_pk_bf16(ar[i][1].x, ar[i][1].y);
        w.u[3] = cvt_pk_bf16(ar[i][1].z, ar[i][1].w);
        *(short8*)(&Alds[0][Adst[i]]) = w.v;
        // prefetch A k-slice for tile 1
        ar[i][0] = *(const float4*)(Asrc[i] + 32);
        ar[i][1] = *(const float4*)(Asrc[i] + 36);
    }
    __syncthreads();   // drains B dma + A ds_write; tile 0 ready

    floatx4 acc[4][4] = {};
    int cur = 0;

    for (int k0 = 0; k0 < Dm; k0 += 32) {
        // stage tile t+1 BEFORE compute of tile t (latency hides under MFMA)
        if (k0 + 32 < Dm) {
            #pragma unroll
            for (int i = 0; i < 2; i++) {
                dma16(Bsrc[i] + k0 + 32, &Blds[cur ^ 1][Bdst[i]]);
                union { short8 v; unsigned int u[4]; } w;
                w.u[0] = cvt_pk_bf16(ar[i][0].x, ar[i][0].y);
                w.u[1] = cvt_pk_bf16(ar[i][0].z, ar[i][0].w);
                w.u[2] = cvt_pk_bf16(ar[i][1].x, ar[i][1].y);
                w.u[3] = cvt_pk_bf16(ar[i][1].z, ar[i][1].w);
                *(short8*)(&Alds[cur ^ 1][Adst[i]]) = w.v;
            }
            if (k0 + 64 < Dm) {
                #pragma unroll
                for (int i = 0; i < 2; i++) {
                    ar[i][0] = *(const float4*)(Asrc[i] + k0 + 64);
                    ar[i][1] = *(const float4*)(Asrc[i] + k0 + 68);
                }
            }
        }

        short8 a[4], b[4];
        #pragma unroll
        for (int r = 0; r < 4; r++) a[r] = *(const short8*)(&Alds[cur][0] + aoff[r]);
        #pragma unroll
        for (int c = 0; c < 4; c++) b[c] = *(const short8*)(&Blds[cur][0] + boff[c]);
        #pragma unroll
        for (int r = 0; r < 4; r++)
            #pragma unroll
            for (int c = 0; c < 4; c++)
                acc[r][c] = __builtin_amdgcn_mfma_f32_16x16x32_bf16(a[r], b[c], acc[r][c], 0, 0, 0);

        __syncthreads();   // one barrier/K-step: drains next-tile staging
        cur ^= 1;
    }

    #pragma unroll
    for (int r = 0; r < 4; r++)
        #pragma unroll
        for (int c = 0; c < 4; c++) {
            int n = n0 + wc * 64 + c * 16 + l16;
            float bias_n = bias[n];
            int h = n >> 6, d = n & 63;
            #pragma unroll
            for (int i = 0; i < 4; i++) {
                int m = m0 + wr * 64 + r * 16 + quad * 4 + i;
                unsigned short ob = f32_to_bf16(acc[r][c][i] + bias_n);
                int bb = m >> 11, s = m & (Ss - 1);
                if (mode == 0)
                    Out[((size_t)(bb * Hh + h) * Ss + s) * 64 + d] = ob;
                else
                    Out[(((size_t)(bb * Hh + h) * 32 + (s >> 6)) * 64 + d) * 64 + (s & 63)] = ob;
            }
        }
}

// ---------------------------------------------------------------------------
// Final GEMM, 2-phase pipelined: AO (8192 x 1024 bf16) @ Wot^T + bo, * q_mask
// -> fp32 d_out. Same single-barrier double-buffered schedule as gemm_proj_f32
// (both operands via global_load_lds).
// ---------------------------------------------------------------------------
__global__ __launch_bounds__(256) void gemm_final(const unsigned short* __restrict__ A,
                                                  const unsigned short* __restrict__ Bt,
                                                  const float* __restrict__ bias,
                                                  const int* __restrict__ q_mask,
                                                  float* __restrict__ Out) {
    const int wave = threadIdx.x >> 6;
    const int lane = threadIdx.x & 63;
    const int quad = lane >> 4;
    const int l16  = lane & 15;
    const int wr = wave & 1, wc = wave >> 1;
    const int m0 = blockIdx.x * 128;
    const int n0 = blockIdx.y * 128;

    __shared__ __align__(16) unsigned short Alds[2][4096];
    __shared__ __align__(16) unsigned short Blds[2][4096];

    const unsigned short* Asrc[2];
    const unsigned short* Bsrc[2];
    int Ldst[2];
    #pragma unroll
    for (int i = 0; i < 2; i++) {
        int L = (wave * 2 + i) * 64 + lane;
        int row = L >> 2, cpr = L & 3;
        int csrc = cpr ^ ((row >> 1) & 3);
        Ldst[i] = (wave * 2 + i) * 512;
        Asrc[i] = A  + (size_t)(m0 + row) * Dm + csrc * 8;
        Bsrc[i] = Bt + (size_t)(n0 + row) * Dm + csrc * 8;
    }

    int aoff[4], boff[4];
    #pragma unroll
    for (int r = 0; r < 4; r++) {
        int row = wr * 64 + r * 16 + l16;
        aoff[r] = row * 32 + (quad ^ ((row >> 1) & 3)) * 8;
        row = wc * 64 + r * 16 + l16;
        boff[r] = row * 32 + (quad ^ ((row >> 1) & 3)) * 8;
    }

    // prologue: stage tile 0
    #pragma unroll
    for (int i = 0; i < 2; i++) {
        dma16(Asrc[i], &Alds[0][Ldst[i]]);
        dma16(Bsrc[i], &Blds[0][Ldst[i]]);
    }
    __syncthreads();

    floatx4 acc[4][4] = {};
    int cur = 0;

    for (int k0 = 0; k0 < Dm; k0 += 32) {
        if (k0 + 32 < Dm) {
            #pragma unroll
            for (int i = 0; i < 2; i++) {
                dma16(Asrc[i] + k0 + 32, &Alds[cur ^ 1][Ldst[i]]);
                dma16(Bsrc[i] + k0 + 32, &Blds[cur ^ 1][Ldst[i]]);
            }
        }

        short8 a[4], b[4];
        #pragma unroll
        for (int r = 0; r < 4; r++) a[r] = *(const short8*)(&Alds[cur][0] + aoff[r]);
        #pragma unroll
        for (int c = 0; c < 4; c++) b[c] = *(const short8*)(&Blds[cur][0] + boff[c]);
        #pragma unroll
        for (int r = 0; r < 4; r++)
            #pragma unroll
            for (int c = 0; c < 4; c++)
                acc[r][c] = __builtin_amdgcn_mfma_f32_16x16x32_bf16(a[r], b[c], acc[r][c], 0, 0, 0);

        __syncthreads();
        cur ^= 1;
    }

    #pragma unroll
    for (int r = 0; r < 4; r++)
        #pragma unroll
        for (int c = 0; c < 4; c++) {
            int n = n0 + wc * 64 + c * 16 + l16;
            float bias_n = bias[n];
            #pragma unroll
            for (int i = 0; i < 4; i++) {
                int m = m0 + wr * 64 + r * 16 + quad * 4 + i;
                float qm = (float)q_mask[m];
                Out[(size_t)m * Dm + n] = (acc[r][c][i] + bias_n) * qm;
            }
        }
}

// ---------------------------------------------------------------------------
// Flash attention, v5 (unchanged from round 4): un-paired blocks +
// dispatch-topology-balanced qt map, 32 q-rows/wave, m=0 softmax,
// register-resident P, MFMA(ones) denominator, C[d][query] output.
// ---------------------------------------------------------------------------
#define SCL 0.18033688f      // 0.125 * log2(e)
#define PEN 1.44269504e12f   // 1e12 * log2(e)  (matches reference NEG_BIG)

__global__ __launch_bounds__(256, 2) void attn_kernel(const unsigned short* __restrict__ Qp,
                                                      const unsigned short* __restrict__ Kp,
                                                      const unsigned short* __restrict__ Vt,
                                                      const int* __restrict__ v_mask,
                                                      unsigned short* __restrict__ AO) {
    const int tid  = threadIdx.x;
    const int wave = tid >> 6;
    const int lane = tid & 63;
    const int quad = lane >> 4;
    const int l16  = lane & 15;

    // balanced block -> (qt, h, b) mapping (see header comment)
    const int n   = blockIdx.x;
    const int hi4 = n >> 8, lo = n & 255;
    const int t2  = (lo >> 6) & 3;
    const int h   = (lo & 63) >> 2;
    const int b   = lo & 3;
    int qt;
    switch (hi4) {
        case 0:  qt = t2;      break;
        case 1:  qt = 15 - t2; break;
        case 2:  qt = 7 - t2;  break;
        default: qt = 8 + t2;  break;
    }
    const int bh = b * Hh + h;

    __shared__ __align__(16) unsigned short Klds[2][4096];
    __shared__ __align__(16) unsigned short Vlds[2][4096];
    __shared__ int allv[32];

    // per-64-key-tile "no masked key" flags (8 threads/tile, 2 int4 each)
    {
        const int tile = tid >> 3, sub = tid & 7;
        const int4 vmA = *(const int4*)(v_mask + b * Ss + tile * 64 + sub * 8);
        const int4 vmB = *(const int4*)(v_mask + b * Ss + tile * 64 + sub * 8 + 4);
        const bool ok = vmA.x && vmA.y && vmA.z && vmA.w &&
                        vmB.x && vmB.y && vmB.z && vmB.w;
        const unsigned long long bal = __ballot(ok);
        if (sub == 0)
            allv[tile] = (int)(((bal >> ((tile & 7) * 8)) & 0xFFull) == 0xFFull);
    }

    // staging: 512 chunks of 16B per 8KB tile; 2 rounds of 256 threads
    // LDS[row][c] = G[row][c ^ f(row)],  f(row) = (row&3)|((row>>1)&4)
    int srcOff[2], ldsDst[2];
    #pragma unroll
    for (int i = 0; i < 2; i++) {
        int G = i * 256 + tid;
        int grow = G >> 3, gc = G & 7;
        int fS = (grow & 3) | ((grow >> 1) & 4);
        srcOff[i] = grow * 64 + (gc ^ fS) * 8;
        ldsDst[i] = i * 2048 + wave * 512;      // + lane*16B implicit
    }
    const unsigned short* Kt_base = Kp + (size_t)bh * Ss * 64;
    const unsigned short* Vt_base = Vt + (size_t)bh * 32 * 4096;
    const int* vm_base = v_mask + b * Ss;

    // K fragment offsets: permuted rows, de-swizzled chunks (wave-independent)
    const int l3 = l16 & 3;
    const int fK = l3 | (((l16 >> 2) & 1) << 2);
    const int kslot = (quad ^ fK) * 8;
    int koff[4];
    #pragma unroll
    for (int kf = 0; kf < 4; kf++) {
        int row = (kf & 1) * 32 + ((l16 >> 2) << 3) + ((kf >> 1) << 2) + l3;
        koff[kf] = row * 64 + kslot;
    }
    // V fragment offsets (A-operand of PV): rows f*16+l16
    const int fV = l3 | (((l16 >> 3) & 1) << 2);
    const int vslot = (quad ^ fV) * 8;
    int voff[4];
    #pragma unroll
    for (int f = 0; f < 4; f++) voff[f] = (f * 16 + l16) * 64 + vslot;

    short8 ones;
    #pragma unroll
    for (int i = 0; i < 8; i++) ones[i] = (short)0x3F80;   // bf16 1.0

    const int kbq = quad * 8;

    const int qbase = qt * 128 + wave * 32;
    const int q0 = qbase + l16;            // frag0 query; frag1 = q0 + 16
    const unsigned short* qptr = Qp + ((size_t)bh * Ss + q0) * 64 + quad * 8;
    const short8 qf0 = *(const short8*)(qptr);
    const short8 qf1 = *(const short8*)(qptr + 32);
    const short8 qg0 = *(const short8*)(qptr + 16 * 64);
    const short8 qg1 = *(const short8*)(qptr + 16 * 64 + 32);

    floatx4 o0[4] = {}, o1[4] = {};
    floatx4 sm0 = {}, sm1 = {};

    const int diagw = 2 * qt + (wave >> 1);
    const int KT    = 2 * qt + 2;

    #pragma unroll
    for (int i = 0; i < 2; i++) {
        dma16(Kt_base + srcOff[i], &Klds[0][ldsDst[i]]);
        dma16(Vt_base + srcOff[i], &Vlds[0][ldsDst[i]]);
    }
    __syncthreads();

    int cur = 0;
    for (int kt = 0; kt < KT; kt++) {
        if (kt + 1 < KT) {
            const unsigned short* kn = Kt_base + (size_t)(kt + 1) * 4096;
            const unsigned short* vn = Vt_base + (size_t)(kt + 1) * 4096;
            #pragma unroll
            for (int i = 0; i < 2; i++) {
                dma16(kn + srcOff[i], &Klds[cur ^ 1][ldsDst[i]]);
                dma16(vn + srcOff[i], &Vlds[cur ^ 1][ldsDst[i]]);
            }
        }

        if (kt <= diagw) {
            const unsigned short* Kc = &Klds[cur][0];
            const unsigned short* Vc = &Vlds[cur][0];
            const int kk = kt * 64;

            floatx4 st0[4], st1[4];
            #pragma unroll
            for (int kf = 0; kf < 4; kf++) {
                short8 a0 = *(const short8*)(Kc + koff[kf]);
                short8 a1 = *(const short8*)(Kc + (koff[kf] ^ 32));
                floatx4 t = {};
                t = __builtin_amdgcn_mfma_f32_16x16x32_bf16(a0, qf0, t, 0, 0, 0);
                t = __builtin_amdgcn_mfma_f32_16x16x32_bf16(a1, qf1, t, 0, 0, 0);
                st0[kf] = t;
                floatx4 u = {};
                u = __builtin_amdgcn_mfma_f32_16x16x32_bf16(a0, qg0, u, 0, 0, 0);
                u = __builtin_amdgcn_mfma_f32_16x16x32_bf16(a1, qg1, u, 0, 0, 0);
                st1[kf] = u;
            }

            unsigned int pk0[4][2], pk1[4][2];
            if ((kt == diagw) || (!allv[kt])) {
                // slow path: diagonal tile and/or v_mask has zeros here
                #pragma unroll
                for (int kf = 0; kf < 4; kf++) {
                    const int kb = kk + (kf & 1) * 32 + kbq + ((kf >> 1) << 2);
                    const int4 vm = *(const int4*)(vm_base + kb);
                    const int vmi[4] = {vm.x, vm.y, vm.z, vm.w};
                    float p0[4], p1[4];
                    #pragma unroll
                    for (int i = 0; i < 4; i++) {
                        const int key = kb + i;
                        const float penm = (vmi[i] == 0) ? PEN : 0.f;
                        const float pe0 = penm + ((key > q0) ? PEN : 0.f);
                        const float pe1 = penm + ((key > q0 + 16) ? PEN : 0.f);
                        p0[i] = exp2f(fmaf(st0[kf][i], SCL, -pe0));
                        p1[i] = exp2f(fmaf(st1[kf][i], SCL, -pe1));
                    }
                    pk0[kf][0] = cvt_pk_bf16(p0[0], p0[1]);
                    pk0[kf][1] = cvt_pk_bf16(p0[2], p0[3]);
                    pk1[kf][0] = cvt_pk_bf16(p1[0], p1[1]);
                    pk1[kf][1] = cvt_pk_bf16(p1[2], p1[3]);
                }
            } else {
                // fast path: no masking possible in this tile
                #pragma unroll
                for (int kf = 0; kf < 4; kf++) {
                    float p0[4], p1[4];
                    #pragma unroll
                    for (int i = 0; i < 4; i++) {
                        p0[i] = exp2f(st0[kf][i] * SCL);
                        p1[i] = exp2f(st1[kf][i] * SCL);
                    }
                    pk0[kf][0] = cvt_pk_bf16(p0[0], p0[1]);
                    pk0[kf][1] = cvt_pk_bf16(p0[2], p0[3]);
                    pk1[kf][0] = cvt_pk_bf16(p1[0], p1[1]);
                    pk1[kf][1] = cvt_pk_bf16(p1[2], p1[3]);
                }
            }

            // P fragments: pX0 = keys kk+quad*8..+7, pX1 = keys kk+32+quad*8..+7
            union { short8 s; unsigned int u[4]; } pA0, pA1, pB0, pB1;
            pA0.u[0] = pk0[0][0]; pA0.u[1] = pk0[0][1];
            pA0.u[2] = pk0[2][0]; pA0.u[3] = pk0[2][1];
            pA1.u[0] = pk0[1][0]; pA1.u[1] = pk0[1][1];
            pA1.u[2] = pk0[3][0]; pA1.u[3] = pk0[3][1];
            pB0.u[0] = pk1[0][0]; pB0.u[1] = pk1[0][1];
            pB0.u[2] = pk1[2][0]; pB0.u[3] = pk1[2][1];
            pB1.u[0] = pk1[1][0]; pB1.u[1] = pk1[1][1];
            pB1.u[2] = pk1[3][0]; pB1.u[3] = pk1[3][1];

            // denominator on the matrix pipe
            sm0 = __builtin_amdgcn_mfma_f32_16x16x32_bf16(ones, pA0.s, sm0, 0, 0, 0);
            sm0 = __builtin_amdgcn_mfma_f32_16x16x32_bf16(ones, pA1.s, sm0, 0, 0, 0);
            sm1 = __builtin_amdgcn_mfma_f32_16x16x32_bf16(ones, pB0.s, sm1, 0, 0, 0);
            sm1 = __builtin_amdgcn_mfma_f32_16x16x32_bf16(ones, pB1.s, sm1, 0, 0, 0);

            #pragma unroll
            for (int f = 0; f < 4; f++) {
                short8 v0 = *(const short8*)(Vc + voff[f]);
                short8 v1 = *(const short8*)(Vc + (voff[f] ^ 32));
                o0[f] = __builtin_amdgcn_mfma_f32_16x16x32_bf16(v0, pA0.s, o0[f], 0, 0, 0);
                o0[f] = __builtin_amdgcn_mfma_f32_16x16x32_bf16(v1, pA1.s, o0[f], 0, 0, 0);
                o1[f] = __builtin_amdgcn_mfma_f32_16x16x32_bf16(v0, pB0.s, o1[f], 0, 0, 0);
                o1[f] = __builtin_amdgcn_mfma_f32_16x16x32_bf16(v1, pB1.s, o1[f], 0, 0, 0);
            }
        }

        __syncthreads();
        cur ^= 1;
    }

    // epilogue: every lane already holds its query's full denominator
    const float ri0 = 1.0f / sm0[0];
    const float ri1 = 1.0f / sm1[0];
    unsigned short* aop0 = AO + ((size_t)b * Ss + q0) * (Hh * DVv) + h * 64 + quad * 4;
    unsigned short* aop1 = aop0 + (size_t)16 * (Hh * DVv);
    #pragma unroll
    for (int f = 0; f < 4; f++) {
        int2 w0, w1;
        w0.x = (int)cvt_pk_bf16(o0[f][0] * ri0, o0[f][1] * ri0);
        w0.y = (int)cvt_pk_bf16(o0[f][2] * ri0, o0[f][3] * ri0);
        *(int2*)(aop0 + f * 16) = w0;
        w1.x = (int)cvt_pk_bf16(o1[f][0] * ri1, o1[f][1] * ri1);
        w1.y = (int)cvt_pk_bf16(o1[f][2] * ri1, o1[f][3] * ri1);
        *(int2*)(aop1 + f * 16) = w1;
    }
}

// ---------------------------------------------------------------------------
extern "C" void kernel_launch(void* const* d_in, const int* in_sizes, int n_in,
                              void* d_out, int out_size, void* d_ws, size_t ws_size,
                              hipStream_t stream) {
    const float* q      = (const float*)d_in[0];
    const float* k      = (const float*)d_in[1];
    const float* v      = (const float*)d_in[2];
    const int*   q_mask = (const int*)d_in[3];
    const int*   v_mask = (const int*)d_in[4];
    const float* Wq     = (const float*)d_in[5];
    const float* bq     = (const float*)d_in[6];
    const float* Wk     = (const float*)d_in[7];
    const float* bk     = (const float*)d_in[8];
    const float* Wv     = (const float*)d_in[9];
    const float* bv     = (const float*)d_in[10];
    const float* Wo     = (const float*)d_in[11];
    const float* bo     = (const float*)d_in[12];
    float* out = (float*)d_out;

    char* ws = (char*)d_ws;
    const size_t WT_SZ = (size_t)Dm * Dm * 2;                 // 2 MB each
    const size_t QP_SZ = (size_t)Bb * Hh * Ss * 64 * 2;       // 16 MB each
    unsigned short* Wtq = (unsigned short*)(ws);
    unsigned short* Wtk = (unsigned short*)(ws + WT_SZ);
    unsigned short* Wtv = (unsigned short*)(ws + 2 * WT_SZ);
    unsigned short* Wto = (unsigned short*)(ws + 3 * WT_SZ);
    unsigned short* Qp  = (unsigned short*)(ws + 4 * WT_SZ);
    unsigned short* Kp  = (unsigned short*)(ws + 4 * WT_SZ + QP_SZ);
    unsigned short* Vt  = (unsigned short*)(ws + 4 * WT_SZ + 2 * QP_SZ);
    unsigned short* AO  = (unsigned short*)(ws + 4 * WT_SZ + 3 * QP_SZ);

    hipLaunchKernelGGL(transpose_w4, dim3(Dm / 32, Dm / 32, 4), dim3(32, 8), 0, stream,
                       Wq, Wk, Wv, Wo, Wtq, Wtk, Wtv, Wto);

    const int M = Bb * Ss;  // 8192
    dim3 gp(M / 128, Dm / 128, 3);
    hipLaunchKernelGGL(gemm_proj_f32, gp, dim3(256), 0, stream,
                       q, k, v, Wtq, Wtk, Wtv, bq, bk, bv, Qp, Kp, Vt);

    dim3 ag(Bb * Hh * (Ss / 128), 1, 1);   // 1024 balanced blocks
    hipLaunchKernelGGL(attn_kernel, ag, dim3(256), 0, stream, Qp, Kp, Vt, v_mask, AO);

    dim3 gg(M / 128, Dm / 128);
    hipLaunchKernelGGL(gemm_final, gg, dim3(256), 0, stream, AO, Wto, bo, q_mask, out);
}